// Round 1
// baseline (459.423 us; speedup 1.0000x reference)
//
#include <hip/hip_runtime.h>

#define HH 2000
#define WW 1000
#define HWSZ (HH * WW)
#define NEG_INF (-3.0e38f)

// ---- monotone float<->uint encoding for atomicMax on floats ----
__device__ __forceinline__ unsigned fenc(float f) {
    unsigned u = __float_as_uint(f);
    return (u & 0x80000000u) ? ~u : (u | 0x80000000u);
}
__device__ __forceinline__ float fdec(unsigned k) {
    unsigned u = (k & 0x80000000u) ? (k & 0x7fffffffu) : ~k;
    return __uint_as_float(u);
}

__global__ void init_buckets(unsigned* __restrict__ buck, int n) {
    int i = blockIdx.x * blockDim.x + threadIdx.x;
    if (i < n) buck[i] = 0u;  // 0 < enc(x) for every real float x
}

__global__ void decode_buckets(unsigned* __restrict__ buck, int n) {
    int i = blockIdx.x * blockDim.x + threadIdx.x;
    if (i < n) {
        unsigned k = buck[i];
        ((float*)buck)[i] = fdec(k);
    }
}

// One fully-unrolled dense layer applied to TWO pixels sharing each weight read.
template <int C, int O, bool RELU>
__device__ __forceinline__ void layer_pair(const float* __restrict__ sw,
                                           const float* __restrict__ sb,
                                           const float* __restrict__ x0,
                                           const float* __restrict__ x1,
                                           float* __restrict__ y0,
                                           float* __restrict__ y1) {
#pragma unroll
    for (int o = 0; o < O; ++o) {
        float a0 = sb[o];
        float a1 = a0;
#pragma unroll
        for (int c = 0; c < C; ++c) {
            float wv = sw[o * C + c];
            a0 = fmaf(wv, x0[c], a0);
            a1 = fmaf(wv, x1[c], a1);
        }
        y0[o] = RELU ? fmaxf(a0, 0.0f) : a0;
        y1[o] = RELU ? fmaxf(a1, 0.0f) : a1;
    }
}

__global__ __launch_bounds__(256, 2) void mlp_max_kernel(
    const float* __restrict__ in,
    const float* __restrict__ w1, const float* __restrict__ b1,
    const float* __restrict__ w2, const float* __restrict__ b2,
    const float* __restrict__ w3, const float* __restrict__ b3,
    const float* __restrict__ w4, const float* __restrict__ b4,
    unsigned* __restrict__ rowbuck, unsigned* __restrict__ colbuck) {
    __shared__ __align__(16) float sw1[18 * 9];
    __shared__ __align__(16) float sw2[36 * 18];
    __shared__ __align__(16) float sw3[36 * 36];
    __shared__ __align__(16) float sw4[36];
    __shared__ float sb1[18], sb2[36], sb3[36], sb4s[1];
    __shared__ float cred[4][64];

    const int tx = threadIdx.x;           // 0..63 (lane)
    const int ty = threadIdx.y;           // 0..3  (wave id)
    const int tid = ty * 64 + tx;

    // stage weights/biases into LDS
    for (int i = tid; i < 162; i += 256) sw1[i] = w1[i];
    for (int i = tid; i < 648; i += 256) sw2[i] = w2[i];
    for (int i = tid; i < 1296; i += 256) sw3[i] = w3[i];
    if (tid < 18) sb1[tid] = b1[tid];
    else if (tid >= 64 && tid < 100) sb2[tid - 64] = b2[tid - 64];
    else if (tid >= 128 && tid < 164) sb3[tid - 128] = b3[tid - 128];
    else if (tid >= 192 && tid < 228) sw4[tid - 192] = w4[tid - 192];
    else if (tid == 255) sb4s[0] = b4[0];
    __syncthreads();

    const int col = blockIdx.x * 64 + tx;   // 0..1023 (>=1000 masked)
    const int rb = blockIdx.y * 32;         // row base of this block's tile

    float colmax = NEG_INF;

    for (int kk = 0; kk < 4; ++kk) {
        const int r0 = rb + kk * 8 + ty;    // wave-uniform row
        const int r1 = r0 + 4;              // wave-uniform row
        const bool v0 = (col < WW) && (r0 < HH);
        const bool v1 = (col < WW) && (r1 < HH);
        const int p0 = v0 ? (r0 * WW + col) : 0;
        const int p1 = v1 ? (r1 * WW + col) : 0;

        float x0[36], x1[36], y0[36], y1[36];
#pragma unroll
        for (int c = 0; c < 9; ++c) {
            x0[c] = in[c * HWSZ + p0];      // coalesced: consecutive tx -> consecutive addr
            x1[c] = in[c * HWSZ + p1];
        }

        layer_pair<9, 18, true>(sw1, sb1, x0, x1, y0, y1);
        layer_pair<18, 36, true>(sw2, sb2, y0, y1, x0, x1);
        layer_pair<36, 36, true>(sw3, sb3, x0, x1, y0, y1);

        float s0 = sb4s[0];
        float s1 = s0;
#pragma unroll
        for (int c = 0; c < 36; ++c) {
            float wv = sw4[c];
            s0 = fmaf(wv, y0[c], s0);
            s1 = fmaf(wv, y1[c], s1);
        }
        s0 = v0 ? s0 : NEG_INF;
        s1 = v1 ? s1 : NEG_INF;
        colmax = fmaxf(colmax, fmaxf(s0, s1));

        // row max: all 64 lanes of this wave share the same row
        float m0 = s0, m1 = s1;
#pragma unroll
        for (int off = 32; off > 0; off >>= 1) {
            m0 = fmaxf(m0, __shfl_xor(m0, off, 64));
            m1 = fmaxf(m1, __shfl_xor(m1, off, 64));
        }
        if (tx == 0) {
            if (r0 < HH) atomicMax(&rowbuck[r0], fenc(m0));
            if (r1 < HH) atomicMax(&rowbuck[r1], fenc(m1));
        }
    }

    // col max: reduce the 4 waves' per-column maxima through LDS
    cred[ty][tx] = colmax;
    __syncthreads();
    if (ty == 0 && col < WW) {
        float m = fmaxf(fmaxf(cred[0][tx], cred[1][tx]),
                        fmaxf(cred[2][tx], cred[3][tx]));
        atomicMax(&colbuck[col], fenc(m));
    }
}

extern "C" void kernel_launch(void* const* d_in, const int* in_sizes, int n_in,
                              void* d_out, int out_size, void* d_ws, size_t ws_size,
                              hipStream_t stream) {
    const float* in = (const float*)d_in[0];
    // d_in[1] = T_out (unused), d_in[2] = T_indices (identity, unused)
    const float* w1 = (const float*)d_in[3];
    const float* b1 = (const float*)d_in[4];
    const float* w2 = (const float*)d_in[5];
    const float* b2 = (const float*)d_in[6];
    const float* w3 = (const float*)d_in[7];
    const float* b3 = (const float*)d_in[8];
    const float* w4 = (const float*)d_in[9];
    const float* b4 = (const float*)d_in[10];

    unsigned* buck = (unsigned*)d_out;  // [0,2000) row maxes, [2000,3000) col maxes

    init_buckets<<<(3000 + 255) / 256, 256, 0, stream>>>(buck, 3000);

    dim3 block(64, 4);
    dim3 grid(16, 63);  // 16*64=1024 >= 1000 cols ; 63*32=2016 >= 2000 rows
    mlp_max_kernel<<<grid, block, 0, stream>>>(in, w1, b1, w2, b2, w3, b3, w4, b4,
                                               buck, buck + 2000);

    decode_buckets<<<(3000 + 255) / 256, 256, 0, stream>>>(buck, 3000);
}

// Round 2
// 408.718 us; speedup vs baseline: 1.1241x; 1.1241x over previous
//
#include <hip/hip_runtime.h>

#define HH 2000
#define WW 1000
#define HWSZ (HH * WW)
#define NEG_INF (-3.0e38f)

// ---- monotone float<->uint encoding for atomicMax on floats ----
__device__ __forceinline__ unsigned fenc(float f) {
    unsigned u = __float_as_uint(f);
    return (u & 0x80000000u) ? ~u : (u | 0x80000000u);
}
__device__ __forceinline__ float fdec(unsigned k) {
    unsigned u = (k & 0x80000000u) ? (k & 0x7fffffffu) : ~k;
    return __uint_as_float(u);
}

__global__ void init_buckets(unsigned* __restrict__ buck, int n) {
    int i = blockIdx.x * blockDim.x + threadIdx.x;
    if (i < n) buck[i] = 0u;  // 0 < enc(x) for every real float x
}

__global__ void decode_buckets(unsigned* __restrict__ buck, int n) {
    int i = blockIdx.x * blockDim.x + threadIdx.x;
    if (i < n) {
        unsigned k = buck[i];
        ((float*)buck)[i] = fdec(k);
    }
}

// One fully-unrolled dense layer, ONE pixel per thread.
// w/b are uniform global pointers with compile-time indices -> the compiler
// emits s_load into SGPRs; v_fma_f32 takes the weight as the SGPR operand.
// Zero VGPR / zero LDS cost for weights.
template <int C, int O, bool RELU>
__device__ __forceinline__ void layer(const float* __restrict__ w,
                                      const float* __restrict__ b,
                                      const float* __restrict__ x,
                                      float* __restrict__ y) {
#pragma unroll
    for (int o = 0; o < O; ++o) {
        float a = b[o];
#pragma unroll
        for (int c = 0; c < C; ++c) {
            a = fmaf(w[o * C + c], x[c], a);
        }
        y[o] = RELU ? fmaxf(a, 0.0f) : a;
    }
}

__global__ __launch_bounds__(256) void mlp_max_kernel(
    const float* __restrict__ in,
    const float* __restrict__ w1, const float* __restrict__ b1,
    const float* __restrict__ w2, const float* __restrict__ b2,
    const float* __restrict__ w3, const float* __restrict__ b3,
    const float* __restrict__ w4, const float* __restrict__ b4,
    unsigned* __restrict__ rowbuck, unsigned* __restrict__ colbuck) {
    __shared__ float cred[4][64];

    const int tx = threadIdx.x;           // 0..63 (lane)
    const int ty = threadIdx.y;           // 0..3  (wave id)

    const int col = blockIdx.x * 64 + tx;   // 0..1023 (>=1000 masked)
    const int rb = blockIdx.y * 32;         // row base of this block's tile
    const bool colok = (col < WW);

    float colmax = NEG_INF;

    for (int kk = 0; kk < 8; ++kk) {
        const int r = rb + kk * 4 + ty;     // wave-uniform row
        const bool v = colok && (r < HH);
        const int p = v ? (r * WW + col) : 0;

        float x[36], y[36];
#pragma unroll
        for (int c = 0; c < 9; ++c) {
            x[c] = in[c * HWSZ + p];        // coalesced across lanes
        }

        layer<9, 18, true>(w1, b1, x, y);
        layer<18, 36, true>(w2, b2, y, x);
        layer<36, 36, true>(w3, b3, x, y);

        float s = b4[0];
#pragma unroll
        for (int c = 0; c < 36; ++c) s = fmaf(w4[c], y[c], s);

        s = v ? s : NEG_INF;
        colmax = fmaxf(colmax, s);

        // row max: all 64 lanes of this wave share the same row r
        float m = s;
#pragma unroll
        for (int off = 32; off > 0; off >>= 1) {
            m = fmaxf(m, __shfl_xor(m, off, 64));
        }
        if (tx == 0 && r < HH) {
            atomicMax(&rowbuck[r], fenc(m));
        }
    }

    // col max: reduce the 4 waves' per-column maxima through LDS
    cred[ty][tx] = colmax;
    __syncthreads();
    if (ty == 0 && colok) {
        float m = fmaxf(fmaxf(cred[0][tx], cred[1][tx]),
                        fmaxf(cred[2][tx], cred[3][tx]));
        atomicMax(&colbuck[col], fenc(m));
    }
}

extern "C" void kernel_launch(void* const* d_in, const int* in_sizes, int n_in,
                              void* d_out, int out_size, void* d_ws, size_t ws_size,
                              hipStream_t stream) {
    const float* in = (const float*)d_in[0];
    // d_in[1] = T_out (unused), d_in[2] = T_indices (identity, unused)
    const float* w1 = (const float*)d_in[3];
    const float* b1 = (const float*)d_in[4];
    const float* w2 = (const float*)d_in[5];
    const float* b2 = (const float*)d_in[6];
    const float* w3 = (const float*)d_in[7];
    const float* b3 = (const float*)d_in[8];
    const float* w4 = (const float*)d_in[9];
    const float* b4 = (const float*)d_in[10];

    unsigned* buck = (unsigned*)d_out;  // [0,2000) row maxes, [2000,3000) col maxes

    init_buckets<<<(3000 + 255) / 256, 256, 0, stream>>>(buck, 3000);

    dim3 block(64, 4);
    dim3 grid(16, 63);  // 16*64=1024 >= 1000 cols ; 63*32=2016 >= 2000 rows
    mlp_max_kernel<<<grid, block, 0, stream>>>(in, w1, b1, w2, b2, w3, b3, w4, b4,
                                               buck, buck + 2000);

    decode_buckets<<<(3000 + 255) / 256, 256, 0, stream>>>(buck, 3000);
}